// Round 5
// baseline (16817.725 us; speedup 1.0000x reference)
//
#include <hip/hip_runtime.h>
#include <hip/hip_fp16.h>
#include <stdint.h>
#include <stddef.h>

// DRNN (dilated 3-layer LSTM), B=128, T=1024, F=128, H=256, dil=[1,2,4].
// R4/R5: MFMA-batched recurrence. 8 groups of 16 batch elements; each group = a
// PAIR of WGs (hf owns dims [hf*128,hf*128+128), all 4 gates). Per step: gates =
// Gtile + h @ Whh^T as 16x16x32 MFMA (M=16 batch, K split own/remote 128+128).
// Wave w owns col-blocks {gt*8+w} -> all 4 gates of dims [16w,16w+16) in one
// lane's accs -> LSTM cell fully in registers. h in XOR-swizzled LDS. Pair
// exchange: single-word relaxed agent atomics {tag32|f16x2}, parity dbuf (R3).
// Input GEMMs: batch-major MFMA writing G directly in rec-native layout.
// R5 fix: h-pair packing shfl exchanged MISMATCHED r (even lane got batch m+2's
// odd dim). Now each lane sends hnew[r^2] so both sides pair the same batch m.

typedef _Float16 f16;
typedef _Float16 v2h __attribute__((ext_vector_type(2)));
typedef _Float16 v8h __attribute__((ext_vector_type(8)));
typedef __fp16 h8_raw __attribute__((ext_vector_type(8)));
typedef float v4f __attribute__((ext_vector_type(4)));
typedef unsigned long long u64;

#define DEVINL static __device__ __forceinline__

DEVINL float sigm(float x) { return 1.0f / (1.0f + __expf(-x)); }
DEVINL float tanh_(float x) {
  x = fminf(fmaxf(x, -15.0f), 15.0f);
  float e = __expf(-2.0f * x);
  return (1.0f - e) / (1.0f + e);
}
DEVINL v2h pack2(float a, float b) {
  return __builtin_bit_cast(v2h, __builtin_amdgcn_cvt_pkrtz(a, b));
}
DEVINL v4f mfma16(v8h a, v8h b, v4f c) {
  return __builtin_amdgcn_mfma_f32_16x16x32_f16(__builtin_bit_cast(h8_raw, a),
                                                __builtin_bit_cast(h8_raw, b), c,
                                                0, 0, 0);
}
// Grec block offset for (group g, chunk-local t, half hf): 8192 f16 per block,
// layout inside: [w 0..7][gt 0..3][lane 0..63][r 0..3] f16.
DEVINL size_t goff(int g, int tloc, int hf) {
  return ((size_t)((g * 256 + tloc) * 2 + hf)) << 13;
}
// hbuf (uint32 LDS): h[16 m][256 dims] as u32-pairs, XOR-swizzled in 16B units:
// dw(m, d2) = m*128 + (((d2>>2) ^ (m&7))<<2) + (d2&3),  d2 = dim/2 in [0,128)
DEVINL int hdw(int m, int d2) {
  return m * 128 + ((((d2 >> 2)) ^ (m & 7)) << 2) + (d2 & 3);
}

// ---------------- prep ----------------

__global__ void k_cvt_x(const float2* __restrict__ src, v2h* __restrict__ dst, int n2) {
  int i = blockIdx.x * blockDim.x + threadIdx.x;
  int st = gridDim.x * blockDim.x;
  for (; i < n2; i += st) {
    float2 v = src[i];
    dst[i] = pack2(v.x, v.y);
  }
}

__global__ void k_prep_w(const float* __restrict__ wih0, const float* __restrict__ whh0,
                         const float* __restrict__ wih1, const float* __restrict__ whh1,
                         const float* __restrict__ wih2, const float* __restrict__ whh2,
                         const float* __restrict__ bi0, const float* __restrict__ bh0,
                         const float* __restrict__ bi1, const float* __restrict__ bh1,
                         const float* __restrict__ bi2, const float* __restrict__ bh2,
                         f16* wih0f, f16* whh0f, f16* wih1f, f16* whh1f,
                         f16* wih2f, f16* whh2f,
                         float* bias0, float* bias1, float* bias2) {
  int i = blockIdx.x * blockDim.x + threadIdx.x;  // grid covers 262144
  if (i < 131072) wih0f[i] = (f16)wih0[i];
  whh0f[i] = (f16)whh0[i];
  wih1f[i] = (f16)wih1[i];
  whh1f[i] = (f16)whh1[i];
  wih2f[i] = (f16)wih2[i];
  whh2f[i] = (f16)whh2[i];
  if (i < 1024) {
    bias0[i] = bi0[i] + bh0[i];
    bias1[i] = bi1[i] + bh1[i];
    bias2[i] = bi2[i] + bh2[i];
  }
}

// ---------------- input GEMM, batch-major (M=16 elems), writes Grec layout ----
// K=128,BBW=8 (layer0) or K=256,BBW=4 (layers1/2; 2 col-halves via ch).
// A addr = A + g*gstr + m*mstr + (t0a+tloc)*tstr + k.  8 t per WG, 8 waves.

template <int K, int BBW>
__launch_bounds__(512, 2)
__global__ void k_gemm_b(const f16* __restrict__ A, size_t gstr, size_t mstr,
                         size_t tstr, int t0a,
                         const f16* __restrict__ W, const float* __restrict__ bias,
                         f16* __restrict__ G) {
  constexpr int NCH = 8 / BBW;  // 1 or 2
  int blk = blockIdx.x;
  int g = blk / (32 * NCH);
  int rem = blk % (32 * NCH);
  int tt = rem / NCH;
  int chBase = (rem % NCH) * 32;
  int tid = threadIdx.x;
  int w = tid >> 6, lane = tid & 63;
  int ln = lane & 15, quad = lane >> 4;

  // B-frags + bias + store offsets
  v8h bf[BBW][K / 32];
  float bv[BBW];
  int sbase[BBW];
#pragma unroll
  for (int p = 0; p < BBW; ++p) {
    int bbg = chBase + w * BBW + p;
    int col = bbg * 16 + ln;
    bv[p] = bias[col];
    const f16* wr = W + (size_t)col * K + quad * 8;
#pragma unroll
    for (int kc = 0; kc < K / 32; ++kc) bf[p][kc] = *(const v8h*)(wr + kc * 32);
    int hf = (col >> 7) & 1, gt = col >> 8, wrk = (col >> 4) & 7;
    sbase[p] = hf * 8192 + ((wrk * 4 + gt) * 64 + lane) * 4;
  }

  for (int i = 0; i < 8; ++i) {
    int tloc = tt * 8 + i;
    const f16* arow = A + (size_t)g * gstr + (size_t)ln * mstr +
                      (size_t)(t0a + tloc) * tstr + quad * 8;
    v8h af[K / 32];
#pragma unroll
    for (int kc = 0; kc < K / 32; ++kc) af[kc] = *(const v8h*)(arow + kc * 32);
    size_t gbase = (size_t)(g * 256 + tloc) * 16384;
#pragma unroll
    for (int p = 0; p < BBW; ++p) {
      v4f acc = {0.0f, 0.0f, 0.0f, 0.0f};
#pragma unroll
      for (int kc = 0; kc < K / 32; ++kc) acc = mfma16(af[kc], bf[p][kc], acc);
      uint2 pk;
      pk.x = __builtin_bit_cast(uint32_t, pack2(acc[0] + bv[p], acc[1] + bv[p]));
      pk.y = __builtin_bit_cast(uint32_t, pack2(acc[2] + bv[p], acc[3] + bv[p]));
      *(uint2*)(G + gbase + sbase[p]) = pk;
    }
  }
}

// ---------------- recurrence (MFMA, M=16) ----------------
// grid 16 x 512. g=blk>>1, hf=blk&1. Wave w, col(gt) = gt*256+hf*128+w*16+ln.
// acc[gt][r] = gate gt for (m=quad*4+r, d=w*16+ln)  -> cell in registers.

template <int LAYER>
__launch_bounds__(512, 2)
__global__ void k_rec_b(const f16* __restrict__ Grec,  // chunk, goff layout
                        const f16* __restrict__ Whh,   // [1024][256] f16
                        int t0, int steps,
                        f16* __restrict__ Hout, float* __restrict__ y,
                        uint32_t* __restrict__ hstate32, float* __restrict__ cstate,
                        u64* __restrict__ hxw) {
  int blk = blockIdx.x;
  int g = blk >> 1, hf = blk & 1;
  int tid = threadIdx.x;
  int w = tid >> 6, lane = tid & 63;
  int ln = lane & 15, quad = lane >> 4;

  __shared__ uint32_t hbuf[16 * 128];  // 8 KB, swizzled
  __shared__ f16 Gt2[2][8192];         // 32 KB, double-buffered G tile

  // weights: B-frags wf[gt][kc], 128 VGPRs
  v8h wf[4][8];
#pragma unroll
  for (int gt = 0; gt < 4; ++gt) {
    int col = gt * 256 + hf * 128 + w * 16 + ln;
    const f16* wr = Whh + (size_t)col * 256 + quad * 8;
#pragma unroll
    for (int kc = 0; kc < 8; ++kc) wf[gt][kc] = *(const v8h*)(wr + kc * 32);
  }

  // init / restore
  float c_st[4];
  {
    int m = tid >> 5, u8 = tid & 31;
    if (t0 == 0) {
      uint4 z = {0u, 0u, 0u, 0u};
      *(uint4*)&hbuf[m * 128 + ((u8 ^ (m & 7)) << 2)] = z;
#pragma unroll
      for (int r = 0; r < 4; ++r) c_st[r] = 0.0f;
    } else {
      uint4 v = *(const uint4*)&hstate32[(size_t)(g * 16 + m) * 128 + u8 * 4];
      *(uint4*)&hbuf[m * 128 + ((u8 ^ (m & 7)) << 2)] = v;
#pragma unroll
      for (int r = 0; r < 4; ++r)
        c_st[r] = cstate[(size_t)(g * 16 + quad * 4 + r) * 256 + hf * 128 + w * 16 + ln];
    }
  }
  // stage Gtile[0]
  {
    const uint4* src = (const uint4*)(Grec + goff(g, 0, hf));
    uint4 a = src[tid * 2], b = src[tid * 2 + 1];
    *(uint4*)&Gt2[0][tid * 16] = a;
    *(uint4*)&Gt2[0][tid * 16 + 8] = b;
  }
  __syncthreads();

  u64* myw = hxw + ((size_t)(g * 2 + hf)) * 2048;
  const u64* pw = hxw + ((size_t)(g * 2 + (1 - hf))) * 2048;

  const int rbase = (lane & 1) * 2;      // even lane: r 0,1; odd: r 2,3
  const int dp_own = w * 8 + (ln >> 1);  // own-half pair index 0..63
  // poll targets: words 2*tid, 2*tid+1 of partner; LDS dest (remote half)
  const int wi0 = tid * 2, wi1 = wi0 + 1;
  const int pm0 = wi0 >> 6, pm1 = wi1 >> 6;
  const int gq0 = (1 - hf) * 64 + (wi0 & 63), gq1 = (1 - hf) * 64 + (wi1 & 63);
  const int pdw0 = hdw(pm0, gq0), pdw1 = hdw(pm1, gq1);

  uint32_t lastpk[2] = {0u, 0u};

  for (int s = 0; s < steps; ++s) {
    const int t = t0 + s;
    const int p = s & 1;

    // prefetch next G tile (global, consumed after barrier 2)
    uint4 ga, gb;
    const bool havenext = (s + 1 < steps);
    if (havenext) {
      const uint4* src = (const uint4*)(Grec + goff(g, s + 1, hf));
      ga = src[tid * 2];
      gb = src[tid * 2 + 1];
    }

    // acc init from Gtile[p]
    v4f acc[4];
#pragma unroll
    for (int gt = 0; gt < 4; ++gt) {
      uint2 gv = *(const uint2*)&Gt2[p][((w * 4 + gt) * 64 + lane) * 4];
      v2h gl = __builtin_bit_cast(v2h, gv.x);
      v2h gh = __builtin_bit_cast(v2h, gv.y);
      acc[gt][0] = (float)gl[0];
      acc[gt][1] = (float)gl[1];
      acc[gt][2] = (float)gh[0];
      acc[gt][3] = (float)gh[1];
    }

    // own-half MFMAs (k dims [hf*128, hf*128+128)) — hides partner latency
#pragma unroll
    for (int kc4 = 0; kc4 < 4; ++kc4) {
      int kc = hf * 4 + kc4;
      v8h af = *(const v8h*)&hbuf[ln * 128 + (((kc * 4 + quad) ^ (ln & 7)) << 2)];
#pragma unroll
      for (int gt = 0; gt < 4; ++gt) acc[gt] = mfma16(af, wf[gt][kc], acc[gt]);
    }

    // import partner half of h_{t-1} (tag+payload in one word, no fences)
    if (s > 0) {
      const u64* p0 = pw + (((t - 1) & 1) << 10);
      u64 v0 = __hip_atomic_load(p0 + wi0, __ATOMIC_RELAXED, __HIP_MEMORY_SCOPE_AGENT);
      u64 v1 = __hip_atomic_load(p0 + wi1, __ATOMIC_RELAXED, __HIP_MEMORY_SCOPE_AGENT);
      while (((int)(v0 >> 32) < t) || ((int)(v1 >> 32) < t)) {
        v0 = __hip_atomic_load(p0 + wi0, __ATOMIC_RELAXED, __HIP_MEMORY_SCOPE_AGENT);
        v1 = __hip_atomic_load(p0 + wi1, __ATOMIC_RELAXED, __HIP_MEMORY_SCOPE_AGENT);
      }
      hbuf[pdw0] = (uint32_t)v0;
      hbuf[pdw1] = (uint32_t)v1;
    }
    __syncthreads();  // hbuf remote half ready

    // remote-half MFMAs
#pragma unroll
    for (int kc4 = 0; kc4 < 4; ++kc4) {
      int kc = (1 - hf) * 4 + kc4;
      v8h af = *(const v8h*)&hbuf[ln * 128 + (((kc * 4 + quad) ^ (ln & 7)) << 2)];
#pragma unroll
      for (int gt = 0; gt < 4; ++gt) acc[gt] = mfma16(af, wf[gt][kc], acc[gt]);
    }

    // LSTM cell in registers (4 cells: m=quad*4+r, d=w*16+ln), gates i,f,g,o
    float hnew[4];
#pragma unroll
    for (int r = 0; r < 4; ++r) {
      float iv = sigm(acc[0][r]);
      float fv = sigm(acc[1][r]);
      float gv = tanh_(acc[2][r]);
      float ov = sigm(acc[3][r]);
      c_st[r] = fv * c_st[r] + iv * gv;
      hnew[r] = ov * tanh_(c_st[r]);
    }

    // Pack (d_even, d_odd) per batch m. Even lane publishes m=q4+{0,1} and needs
    // partner's SAME-m values, so each lane SENDS hnew[r^2] (what partner needs)
    // and keeps hnew[r]. (R4 bug: sent hnew[r] -> paired m with m+2.)
    {
      bool odd = (lane & 1) != 0;
      float send0 = odd ? hnew[0] : hnew[2];
      float send1 = odd ? hnew[1] : hnew[3];
      float keep0 = odd ? hnew[2] : hnew[0];
      float keep1 = odd ? hnew[3] : hnew[1];
      float r0 = __shfl_xor(send0, 1, 64);
      float r1 = __shfl_xor(send1, 1, 64);
      v2h pr0 = odd ? pack2(r0, keep0) : pack2(keep0, r0);
      v2h pr1 = odd ? pack2(r1, keep1) : pack2(keep1, r1);
      uint32_t pk0 = __builtin_bit_cast(uint32_t, pr0);
      uint32_t pk1 = __builtin_bit_cast(uint32_t, pr1);
      int m0 = quad * 4 + rbase;  // rbase = odd?2:0
      u64 tg = (u64)(uint32_t)(t + 1) << 32;
      __hip_atomic_store(&myw[((size_t)(t & 1) << 10) + m0 * 64 + dp_own],
                         tg | (u64)pk0, __ATOMIC_RELAXED, __HIP_MEMORY_SCOPE_AGENT);
      __hip_atomic_store(&myw[((size_t)(t & 1) << 10) + (m0 + 1) * 64 + dp_own],
                         tg | (u64)pk1, __ATOMIC_RELAXED, __HIP_MEMORY_SCOPE_AGENT);
      hbuf[hdw(m0, hf * 64 + dp_own)] = pk0;
      hbuf[hdw(m0 + 1, hf * 64 + dp_own)] = pk1;
      lastpk[0] = pk0;
      lastpk[1] = pk1;
    }

    // layer outputs
    if (LAYER == 0) {
      if ((t & 1) == 0) {
        int te = t >> 1;
        size_t base = (size_t)(g * 512 + te) * 16 * 256 + hf * 128 + w * 16 + ln;
#pragma unroll
        for (int r = 0; r < 4; ++r)
          Hout[base + (size_t)(quad * 4 + r) * 256] = (f16)hnew[r];
      }
    } else if (LAYER == 1) {
      if ((t & 1) == 0) {
        int te = t >> 1;
        size_t base = (size_t)(g * 256 + te) * 16 * 256 + hf * 128 + w * 16 + ln;
#pragma unroll
        for (int r = 0; r < 4; ++r)
          Hout[base + (size_t)(quad * 4 + r) * 256] = (f16)hnew[r];
      }
    } else {
      size_t base = ((size_t)(g * 16) * 1024 + (size_t)t * 4) * 256 + hf * 128 + w * 16 + ln;
#pragma unroll
      for (int r = 0; r < 4; ++r) {
        size_t b2 = base + (size_t)(quad * 4 + r) * 1024 * 256;
        float hv = hnew[r];
        y[b2] = hv;
        y[b2 + 256] = hv;
        y[b2 + 512] = hv;
        y[b2 + 768] = hv;
      }
    }

    // stage next G tile
    if (havenext) {
      *(uint4*)&Gt2[p ^ 1][tid * 16] = ga;
      *(uint4*)&Gt2[p ^ 1][tid * 16 + 8] = gb;
    }
    __syncthreads();  // own hbuf + Gtile ready for next step
  }

  // save chunk state (own half; partner WG writes its half)
#pragma unroll
  for (int j = 0; j < 2; ++j) {
    int m = quad * 4 + rbase + j;
    hstate32[(size_t)(g * 16 + m) * 128 + hf * 64 + dp_own] = lastpk[j];
  }
#pragma unroll
  for (int r = 0; r < 4; ++r)
    cstate[(size_t)(g * 16 + quad * 4 + r) * 256 + hf * 128 + w * 16 + ln] = c_st[r];
}

// ---------------- orchestration ----------------

extern "C" void kernel_launch(void* const* d_in, const int* in_sizes, int n_in,
                              void* d_out, int out_size, void* d_ws, size_t ws_size,
                              hipStream_t stream) {
  const float* x = (const float*)d_in[0];
  const float* wih[3] = {(const float*)d_in[1], (const float*)d_in[5], (const float*)d_in[9]};
  const float* whh[3] = {(const float*)d_in[2], (const float*)d_in[6], (const float*)d_in[10]};
  const float* bi[3] = {(const float*)d_in[3], (const float*)d_in[7], (const float*)d_in[11]};
  const float* bh[3] = {(const float*)d_in[4], (const float*)d_in[8], (const float*)d_in[12]};
  float* y = (float*)d_out;

  // workspace (~155 MB)
  char* p = (char*)d_ws;
  f16* Xf = (f16*)p;        p += (size_t)16777216 * 2;        // 33.5 MB
  f16* Wih0f = (f16*)p;     p += (size_t)131072 * 2;
  f16* Whh0f = (f16*)p;     p += (size_t)262144 * 2;
  f16* Wih1f = (f16*)p;     p += (size_t)262144 * 2;
  f16* Whh1f = (f16*)p;     p += (size_t)262144 * 2;
  f16* Wih2f = (f16*)p;     p += (size_t)262144 * 2;
  f16* Whh2f = (f16*)p;     p += (size_t)262144 * 2;
  float* bias0 = (float*)p; p += 4096;
  float* bias1 = (float*)p; p += 4096;
  float* bias2 = (float*)p; p += 4096;
  f16* Gbuf = (f16*)p;      p += (size_t)8 * 256 * 16384 * 2; // 67 MB chunk
  f16* H0e = (f16*)p;       p += (size_t)8 * 512 * 16 * 256 * 2; // 33.5 MB
  f16* H1q = (f16*)p;       p += (size_t)8 * 256 * 16 * 256 * 2; // 16.8 MB
  uint32_t* hstate32 = (uint32_t*)p; p += (size_t)128 * 128 * 4; // 64 KB
  float* cstate = (float*)p; p += (size_t)128 * 256 * 4;         // 128 KB
  u64* hxw0 = (u64*)p;      p += (size_t)16 * 2048 * 8;  // 256 KB (poison tag<0 ok)
  u64* hxw1 = (u64*)p;      p += (size_t)16 * 2048 * 8;
  u64* hxw2 = (u64*)p;      p += (size_t)16 * 2048 * 8;

  k_cvt_x<<<4096, 256, 0, stream>>>((const float2*)x, (v2h*)Xf, 8388608);
  k_prep_w<<<1024, 256, 0, stream>>>(wih[0], whh[0], wih[1], whh[1], wih[2], whh[2],
                                     bi[0], bh[0], bi[1], bh[1], bi[2], bh[2],
                                     Wih0f, Whh0f, Wih1f, Whh1f, Wih2f, Whh2f,
                                     bias0, bias1, bias2);

  // layer 0: x (K=128), 4 chunks of 256 steps
  for (int c = 0; c < 4; ++c) {
    k_gemm_b<128, 8><<<256, 512, 0, stream>>>(Xf, (size_t)16 * 1024 * 128,
                                              (size_t)1024 * 128, 128, c * 256,
                                              Wih0f, bias0, Gbuf);
    k_rec_b<0><<<16, 512, 0, stream>>>(Gbuf, Whh0f, c * 256, 256, H0e, nullptr,
                                       hstate32, cstate, hxw0);
  }
  // layer 1: H0e (K=256), 2 chunks
  for (int c = 0; c < 2; ++c) {
    k_gemm_b<256, 4><<<512, 512, 0, stream>>>(H0e, (size_t)512 * 16 * 256,
                                              256, (size_t)16 * 256, c * 256,
                                              Wih1f, bias1, Gbuf);
    k_rec_b<1><<<16, 512, 0, stream>>>(Gbuf, Whh1f, c * 256, 256, H1q, nullptr,
                                       hstate32, cstate, hxw1);
  }
  // layer 2: H1q (K=256), 1 chunk; writes y with 4x time broadcast
  k_gemm_b<256, 4><<<512, 512, 0, stream>>>(H1q, (size_t)256 * 16 * 256,
                                            256, (size_t)16 * 256, 0,
                                            Wih2f, bias2, Gbuf);
  k_rec_b<2><<<16, 512, 0, stream>>>(Gbuf, Whh2f, 0, 256, nullptr, y,
                                     hstate32, cstate, hxw2);
}